// Round 1
// baseline (532.262 us; speedup 1.0000x reference)
//
#include <hip/hip_runtime.h>
#include <cmath>

#define BB 2
#define KK 12
#define HH 120
#define WW 160
#define HW (HH*WW)
#define DD 128
#define NB 100
#define DMAXF 6.0f
#define NLINES (BB*DD*DD)
#define NVOX (BB*DD*DD*DD)

// ---------------- K1: per-pixel softmax/argmax/depth-index ----------------
__global__ void k1_pixel(const float* __restrict__ sem2d, const float* __restrict__ depth,
                         float* __restrict__ feats_sm, float* __restrict__ stuffflag,
                         int* __restrict__ di_arr) {
    int t = blockIdx.x * blockDim.x + threadIdx.x;
    if (t >= BB * HW) return;
    int b = t / HW, p = t - b * HW;
    const float* sp = sem2d + (size_t)b * KK * HW + p;
    float v[KK];
    float mx = -INFINITY; int am = 0;
#pragma unroll
    for (int k = 0; k < KK; k++) {
        v[k] = sp[(size_t)k * HW];
        if (v[k] > mx) { mx = v[k]; am = k; }
    }
    float s = 0.f;
#pragma unroll
    for (int k = 0; k < KK; k++) { v[k] = expf(v[k] - mx); s += v[k]; }
    float inv = 1.f / s;
    float* fp = feats_sm + (size_t)b * KK * HW + p;
#pragma unroll
    for (int k = 0; k < KK; k++) fp[(size_t)k * HW] = v[k] * inv;
    stuffflag[t] = (am >= 10) ? 1.f : 0.f;
    float d = fminf(depth[t], DMAXF);
    di_arr[t] = (int)((d / DMAXF) * 100.0f);   // exact op order: div then mul
}

// ---------------- K2: 5x5 erosion -> stuff_depth ----------------
__global__ void k2_erode(const float* __restrict__ stuffflag, const float* __restrict__ depth,
                         float* __restrict__ stuff_depth) {
    int t = blockIdx.x * blockDim.x + threadIdx.x;
    if (t >= BB * HW) return;
    int b = t / HW, p = t - b * HW;
    int h = p / WW, w = p - h * WW;
    bool all1 = true;
    for (int dh = -2; dh <= 2; dh++) {
        int hh = h + dh; if (hh < 0 || hh >= HH) continue;
        for (int dw = -2; dw <= 2; dw++) {
            int ww = w + dw; if (ww < 0 || ww >= WW) continue;
            all1 = all1 && (stuffflag[b * HW + hh * WW + ww] > 0.5f);
        }
    }
    float d = fminf(depth[t], DMAXF);
    stuff_depth[t] = all1 ? d : 0.f;
}

// ---------------- K3: per-batch border fills + row/col max + find_none ----------------
__global__ void k3_lines(const float* __restrict__ sd, float* __restrict__ stuff_x,
                         float* __restrict__ stuff_y) {
    __shared__ float ymax[HH], xmax[WW], colmax[WW], rowmax[HH];
    __shared__ float sfxc[WW], sfxr[HH];
    __shared__ float vv[4];
    int b = blockIdx.x;
    int t = threadIdx.x;
    const float* base = sd + (size_t)b * HW;

    if (t < HH) { float m = -INFINITY; for (int w = 0; w < WW; w++) m = fmaxf(m, base[t * WW + w]); ymax[t] = m; }
    if (t < WW) { float m = -INFINITY; for (int h = 0; h < HH; h++) m = fmaxf(m, base[h * WW + t]); xmax[t] = m; }
    __syncthreads();

    if (t == 0) {
        float f = 0.f, l = 0.f;
        for (int h = 0; h < HH; h++) { if (ymax[h] != 0.f) { f = ymax[h]; break; } }
        for (int h = HH - 1; h >= 0; h--) { if (ymax[h] != 0.f) { l = ymax[h]; break; } }
        vv[0] = f; vv[1] = l;
    }
    if (t == 1) {
        float f = 0.f, l = 0.f;
        for (int w = 0; w < WW; w++) { if (xmax[w] != 0.f) { f = xmax[w]; break; } }
        for (int w = WW - 1; w >= 0; w--) { if (xmax[w] != 0.f) { l = xmax[w]; break; } }
        vv[2] = f; vv[3] = l;
    }
    __syncthreads();
    float v1 = vv[0], v2 = vv[1], v3 = vv[2], v4 = vv[3];

    // fill order matches reference: col updates (last) override row updates at corners
    auto sdval = [&](int h, int w) -> float {
        float x = base[h * WW + w];
        if (w == 0)      return (x == 0.f) ? v3 : x;
        if (w == WW - 1) return (x == 0.f) ? v4 : x;
        if (h == 0)      return (x == 0.f) ? v1 : x;
        if (h == HH - 1) return (x == 0.f) ? v2 : x;
        return x;
    };
    if (t < WW) { float m = -INFINITY; for (int h = 0; h < HH; h++) m = fmaxf(m, sdval(h, t)); colmax[t] = m; }
    if (t < HH) { float m = -INFINITY; for (int w = 0; w < WW; w++) m = fmaxf(m, sdval(t, w)); rowmax[t] = m; }
    __syncthreads();

    if (t == 0) {  // find_none on colmax (len W) -> stuff_x
        float m = INFINITY;
        for (int i = WW - 1; i >= 0; i--) { sfxc[i] = m; float a = colmax[i]; if (a != 0.f) m = fminf(m, a); }
        m = INFINITY;
        for (int i = 0; i < WW; i++) {
            float a = colmax[i];
            float l = (m == INFINITY) ? 0.f : m;
            float r = (sfxc[i] == INFINITY) ? 0.f : sfxc[i];
            float val = (a == 0.f) ? fmaxf(l, r) : a;
            if (val != 0.f) m = fminf(m, val);
            stuff_x[b * WW + i] = val;
        }
    }
    if (t == 1) {  // find_none on rowmax (len H) -> stuff_y
        float m = INFINITY;
        for (int i = HH - 1; i >= 0; i--) { sfxr[i] = m; float a = rowmax[i]; if (a != 0.f) m = fminf(m, a); }
        m = INFINITY;
        for (int i = 0; i < HH; i++) {
            float a = rowmax[i];
            float l = (m == INFINITY) ? 0.f : m;
            float r = (sfxr[i] == INFINITY) ? 0.f : sfxr[i];
            float val = (a == 0.f) ? fmaxf(l, r) : a;
            if (val != 0.f) m = fminf(m, val);
            stuff_y[b * HH + i] = val;
        }
    }
}

// ---------------- K3b: per-pixel depth_max_bins ----------------
__global__ void k3b_dmb(const float* __restrict__ stuff_x, const float* __restrict__ stuff_y,
                        int* __restrict__ dmb_arr) {
    int t = blockIdx.x * blockDim.x + threadIdx.x;
    if (t >= BB * HW) return;
    int b = t / HW, p = t - b * HW;
    int h = p / WW, w = p - h * WW;
    float dm = fminf(stuff_x[b * WW + w], stuff_y[b * HH + h]);
    dmb_arr[t] = (int)((dm / DMAXF) * 100.0f);
}

// ---------------- K4: features writer (the big one) ----------------
__global__ void k4_features(const float* __restrict__ occ, const float* __restrict__ feats_sm,
                            const int* __restrict__ di_arr, const int* __restrict__ dmb_arr,
                            float* __restrict__ out) {
    int t = blockIdx.x * blockDim.x + threadIdx.x;
    if (t >= BB * NB * HW) return;
    int b = t / (NB * HW);
    int r = t - b * NB * HW;
    int bin = r / HW;
    int p = r - bin * HW;
    int di = di_arr[b * HW + p];
    int db = dmb_arr[b * HW + p];
    float o = occ[t];
    bool dwk = (bin > di - 3) && (bin < db + 5);
    float sg = 1.f / (1.f + expf(-o));
    float dw = dwk ? sg : 0.f;
    float df = ((float)(bin - di)) / 100.0f * DMAXF;
    float sgn = (float)((bin > di) - (bin < di));
    size_t base = ((size_t)b * 15 * NB + bin) * HW + p;
    const float* fp = feats_sm + (size_t)b * KK * HW + p;
#pragma unroll
    for (int c = 0; c < KK; c++) out[base + (size_t)c * NB * HW] = fp[(size_t)c * HW];
    out[base + (size_t)12 * NB * HW] = dw;
    out[base + (size_t)13 * NB * HW] = sgn;
    out[base + (size_t)14 * NB * HW] = fabsf(df);
}

// ---------------- K5: voxel gather + bit-pack (grid must be exact: no early return, ballot) ----
__global__ void k5_gather(const int* __restrict__ kept, const float4* __restrict__ mapping,
                          const int* __restrict__ di_arr, const int* __restrict__ dmb_arr,
                          float* __restrict__ out_fk, unsigned int* __restrict__ fk_pk,
                          unsigned int* __restrict__ kept_pk) {
    int v = blockIdx.x * blockDim.x + threadIdx.x;
    float4 m = mapping[v];
    int bi = (int)m.x, xi = (int)m.y, yi = (int)m.z;
    int dIdx = (int)((m.w * 100.0f) / DMAXF);   // exact op order: mul then div
    int kp = kept[v];
    int pp = bi * HW + yi * WW + xi;
    int di = di_arr[pp], db = dmb_arr[pp];
    bool dwk = (dIdx > di - 3) && (dIdx < db + 5);
    bool fk = (kp != 0) && dwk;
    out_fk[v] = fk ? 1.f : 0.f;
    unsigned long long mb = __ballot(fk);
    unsigned long long mk = __ballot(kp != 0);
    int lane = threadIdx.x & 63;
    if (lane == 0)  { fk_pk[v >> 5] = (unsigned int)mb;         kept_pk[v >> 5] = (unsigned int)mk; }
    if (lane == 32) { fk_pk[v >> 5] = (unsigned int)(mb >> 32); kept_pk[v >> 5] = (unsigned int)(mk >> 32); }
}

// ---------------- bitwise 128-bit k-dilation ----------------
__device__ inline void kdil128(unsigned int w0, unsigned int w1, unsigned int w2, unsigned int w3,
                               unsigned int* r) {
    unsigned int a0 = w0, a1 = w1, a2 = w2, a3 = w3;
    a0 |= w0 << 1; a1 |= (w1 << 1) | (w0 >> 31); a2 |= (w2 << 1) | (w1 >> 31); a3 |= (w3 << 1) | (w2 >> 31);
    a0 |= w0 << 2; a1 |= (w1 << 2) | (w0 >> 30); a2 |= (w2 << 2) | (w1 >> 30); a3 |= (w3 << 2) | (w2 >> 30);
    a0 |= (w0 >> 1) | (w1 << 31); a1 |= (w1 >> 1) | (w2 << 31); a2 |= (w2 >> 1) | (w3 << 31); a3 |= w3 >> 1;
    a0 |= (w0 >> 2) | (w1 << 30); a1 |= (w1 >> 2) | (w2 << 30); a2 |= (w2 >> 2) | (w3 << 30); a3 |= w3 >> 2;
    r[0] = a0; r[1] = a1; r[2] = a2; r[3] = a3;
}

// ---------------- K6: dilate along j, then k (per line) ----------------
__global__ void k6_dil_jk(const uint4* __restrict__ in, uint4* __restrict__ outb) {
    int l = blockIdx.x * blockDim.x + threadIdx.x;
    if (l >= NLINES) return;
    int b = l / (DD * DD); int rem = l - b * DD * DD; int i = rem / DD; int j = rem - i * DD;
    unsigned int a0 = 0, a1 = 0, a2 = 0, a3 = 0;
    for (int dj = -2; dj <= 2; dj++) {
        int jj = j + dj; if (jj < 0 || jj >= DD) continue;
        uint4 x = in[(b * DD + i) * DD + jj];
        a0 |= x.x; a1 |= x.y; a2 |= x.z; a3 |= x.w;
    }
    unsigned int r[4];
    kdil128(a0, a1, a2, a3, r);
    outb[l] = make_uint4(r[0], r[1], r[2], r[3]);
}

// ---------------- K7: dilate along i, AND kept, popcount -> counters ----------------
__global__ void k7_dil_i_count(const uint4* __restrict__ tmp1, const uint4* __restrict__ kept_pk,
                               uint4* __restrict__ pad0, int* __restrict__ counters) {
    int l = blockIdx.x * blockDim.x + threadIdx.x;
    if (l >= NLINES) return;
    int b = l / (DD * DD); int rem = l - b * DD * DD; int i = rem / DD; int j = rem - i * DD;
    unsigned int a0 = 0, a1 = 0, a2 = 0, a3 = 0;
    for (int di = -2; di <= 2; di++) {
        int ii = i + di; if (ii < 0 || ii >= DD) continue;
        uint4 x = tmp1[(b * DD + ii) * DD + j];
        a0 |= x.x; a1 |= x.y; a2 |= x.z; a3 |= x.w;
    }
    uint4 kk = kept_pk[l];
    a0 &= kk.x; a1 &= kk.y; a2 &= kk.z; a3 &= kk.w;
    pad0[l] = make_uint4(a0, a1, a2, a3);
    int c = __popc(a0) + __popc(a1) + __popc(a2) + __popc(a3);
    for (int off = 32; off; off >>= 1) c += __shfl_down(c, off);
    if ((threadIdx.x & 63) == 0) atomicAdd(&counters[b], c);
}

// ---------------- K8a: special-set + remove feat_kept ----------------
__global__ void k8a_finalize(uint4* __restrict__ pad, const uint4* __restrict__ fk_pk,
                             const int* __restrict__ counters) {
    int l = blockIdx.x * blockDim.x + threadIdx.x;
    if (l >= NLINES) return;
    int b = l / (DD * DD); int rem = l - b * DD * DD; int i = rem / DD; int j = rem - i * DD;
    uint4 p = pad[l];
    if (counters[b] == 0 && i == 127 && j == 127) p.w |= 0x80000000u;  // bit 127
    uint4 f = fk_pk[l];
    p.x &= ~f.x; p.y &= ~f.y; p.z &= ~f.z; p.w &= ~f.w;
    pad[l] = p;
}

// ---------------- K8b: 2x2x2 block-any -> even coords -> union ----------------
__global__ void k8b_union(const uint4* __restrict__ pad, const uint4* __restrict__ fk_pk,
                          uint4* __restrict__ uni) {
    int l = blockIdx.x * blockDim.x + threadIdx.x;
    if (l >= NLINES) return;
    int b = l / (DD * DD); int rem = l - b * DD * DD; int i = rem / DD; int j = rem - i * DD;
    uint4 u = fk_pk[l];
    if (((i | j) & 1) == 0) {
        uint4 la = pad[(b * DD + i) * DD + j];
        uint4 lb = pad[(b * DD + i) * DD + j + 1];
        uint4 lc = pad[(b * DD + i + 1) * DD + j];
        uint4 ld = pad[(b * DD + i + 1) * DD + j + 1];
        unsigned int q0 = la.x | lb.x | lc.x | ld.x;
        unsigned int q1 = la.y | lb.y | lc.y | ld.y;
        unsigned int q2 = la.z | lb.z | lc.z | ld.z;
        unsigned int q3 = la.w | lb.w | lc.w | ld.w;
        q0 = (q0 | (q0 >> 1)) & 0x55555555u;
        q1 = (q1 | (q1 >> 1)) & 0x55555555u;
        q2 = (q2 | (q2 >> 1)) & 0x55555555u;
        q3 = (q3 | (q3 >> 1)) & 0x55555555u;
        u.x |= q0; u.y |= q1; u.z |= q2; u.w |= q3;
    }
    uni[l] = u;
}

// ---------------- K10: dilate along i (plain) ----------------
__global__ void k10_dil_i(const uint4* __restrict__ tmp1, uint4* __restrict__ outb) {
    int l = blockIdx.x * blockDim.x + threadIdx.x;
    if (l >= NLINES) return;
    int b = l / (DD * DD); int rem = l - b * DD * DD; int i = rem / DD; int j = rem - i * DD;
    unsigned int a0 = 0, a1 = 0, a2 = 0, a3 = 0;
    for (int di = -2; di <= 2; di++) {
        int ii = i + di; if (ii < 0 || ii >= DD) continue;
        uint4 x = tmp1[(b * DD + ii) * DD + j];
        a0 |= x.x; a1 |= x.y; a2 |= x.z; a3 |= x.w;
    }
    outb[l] = make_uint4(a0, a1, a2, a3);
}

// ---------------- K11: unpack mask bits -> floats ----------------
__global__ void k11_unpack(const unsigned int* __restrict__ mp, float* __restrict__ outm) {
    int v = blockIdx.x * blockDim.x + threadIdx.x;
    if (v >= NVOX) return;
    outm[v] = ((mp[v >> 5] >> (v & 31)) & 1u) ? 1.f : 0.f;
}

extern "C" void kernel_launch(void* const* d_in, const int* in_sizes, int n_in,
                              void* d_out, int out_size, void* d_ws, size_t ws_size,
                              hipStream_t stream) {
    (void)in_sizes; (void)n_in; (void)out_size; (void)ws_size;
    const float* sem2d   = (const float*)d_in[0];
    const float* depth   = (const float*)d_in[1];
    const float* occ     = (const float*)d_in[2];
    const int*   kept    = (const int*)d_in[3];
    const float* mapping = (const float*)d_in[4];
    float* out = (float*)d_out;

    // workspace carve-up (16B-aligned transitions verified)
    float* feats_sm    = (float*)d_ws;                 // B*K*HW
    float* stuffflag   = feats_sm + BB * KK * HW;      // B*HW
    float* stuff_depth = stuffflag + BB * HW;          // B*HW
    int*   di_arr      = (int*)(stuff_depth + BB * HW);// B*HW
    int*   dmb_arr     = di_arr + BB * HW;             // B*HW
    float* stuff_x     = (float*)(dmb_arr + BB * HW);  // B*W
    float* stuff_y     = stuff_x + BB * WW;            // B*H
    unsigned int* fk_pk   = (unsigned int*)(stuff_y + BB * HH); // NVOX/32 each
    unsigned int* kept_pk = fk_pk + NVOX / 32;
    unsigned int* tmp1    = kept_pk + NVOX / 32;
    unsigned int* pad0    = tmp1 + NVOX / 32;
    unsigned int* uni     = pad0 + NVOX / 32;
    int* counters = (int*)(uni + NVOX / 32);

    hipMemsetAsync(counters, 0, BB * sizeof(int), stream);

    int pixBlocks = (BB * HW + 255) / 256;
    k1_pixel<<<pixBlocks, 256, 0, stream>>>(sem2d, depth, feats_sm, stuffflag, di_arr);
    k2_erode<<<pixBlocks, 256, 0, stream>>>(stuffflag, depth, stuff_depth);
    k3_lines<<<BB, 256, 0, stream>>>(stuff_depth, stuff_x, stuff_y);
    k3b_dmb<<<pixBlocks, 256, 0, stream>>>(stuff_x, stuff_y, dmb_arr);

    k4_features<<<(BB * NB * HW + 255) / 256, 256, 0, stream>>>(occ, feats_sm, di_arr, dmb_arr, out);

    k5_gather<<<NVOX / 256, 256, 0, stream>>>(kept, (const float4*)mapping, di_arr, dmb_arr,
                                              out + (size_t)57600000, fk_pk, kept_pk);

    int lineBlocks = (NLINES + 255) / 256;
    k6_dil_jk<<<lineBlocks, 256, 0, stream>>>((const uint4*)fk_pk, (uint4*)tmp1);
    k7_dil_i_count<<<lineBlocks, 256, 0, stream>>>((const uint4*)tmp1, (const uint4*)kept_pk,
                                                   (uint4*)pad0, counters);
    k8a_finalize<<<lineBlocks, 256, 0, stream>>>((uint4*)pad0, (const uint4*)fk_pk, counters);
    k8b_union<<<lineBlocks, 256, 0, stream>>>((const uint4*)pad0, (const uint4*)fk_pk, (uint4*)uni);
    k6_dil_jk<<<lineBlocks, 256, 0, stream>>>((const uint4*)uni, (uint4*)tmp1);
    k10_dil_i<<<lineBlocks, 256, 0, stream>>>((const uint4*)tmp1, (uint4*)pad0);
    k11_unpack<<<NVOX / 256, 256, 0, stream>>>(pad0, out + (size_t)61794304);
}

// Round 2
// 521.301 us; speedup vs baseline: 1.0210x; 1.0210x over previous
//
#include <hip/hip_runtime.h>
#include <cmath>

#define BB 2
#define KK 12
#define HH 120
#define WW 160
#define HW (HH*WW)
#define DD 128
#define NB 100
#define DMAXF 6.0f
#define NLINES (BB*DD*DD)
#define NVOX (BB*DD*DD*DD)
#define SDP 161   // padded LDS row stride: 161%32==1 -> conflict-free column reads

// ---------------- K1: per-pixel softmax/argmax/depth-index ----------------
__global__ void k1_pixel(const float* __restrict__ sem2d, const float* __restrict__ depth,
                         float* __restrict__ feats_sm, float* __restrict__ stuffflag,
                         int* __restrict__ di_arr) {
    int t = blockIdx.x * blockDim.x + threadIdx.x;
    if (t >= BB * HW) return;
    int b = t / HW, p = t - b * HW;
    const float* sp = sem2d + (size_t)b * KK * HW + p;
    float v[KK];
    float mx = -INFINITY; int am = 0;
#pragma unroll
    for (int k = 0; k < KK; k++) {
        v[k] = sp[(size_t)k * HW];
        if (v[k] > mx) { mx = v[k]; am = k; }
    }
    float s = 0.f;
#pragma unroll
    for (int k = 0; k < KK; k++) { v[k] = expf(v[k] - mx); s += v[k]; }
    float inv = 1.f / s;
    float* fp = feats_sm + (size_t)b * KK * HW + p;
#pragma unroll
    for (int k = 0; k < KK; k++) fp[(size_t)k * HW] = v[k] * inv;
    stuffflag[t] = (am >= 10) ? 1.f : 0.f;
    float d = fminf(depth[t], DMAXF);
    di_arr[t] = (int)((d / DMAXF) * 100.0f);   // exact op order: div then mul
}

// ---------------- K23: fused erosion + border fill + find_none + dmb (one block per batch) ----
__global__ __launch_bounds__(256) void k23_stuff(const float* __restrict__ stuffflag,
                                                 const float* __restrict__ depth,
                                                 int* __restrict__ dmb_arr) {
    __shared__ float sd[HH * SDP];          // 77.3 KB
    __shared__ unsigned int bA[600];        // packed stuff bits (5 words/row)
    __shared__ unsigned int bB[600];        // horizontally eroded bits
    __shared__ float ymax[HH], xmax[WW], colmax[WW], rowmax[HH];
    __shared__ float sufc[WW], sufr[HH];
    __shared__ float sxv[WW], syv[HH];
    __shared__ float vv[4];
    int b = blockIdx.x, t = threadIdx.x;
    const float* sf = stuffflag + b * HW;
    const float* dp = depth + b * HW;

    // pack stuff flags into bits via ballot (coalesced reads)
    for (int it = 0; it < HW / 256; ++it) {
        int p = it * 256 + t;
        bool fl = sf[p] > 0.5f;
        unsigned long long m = __ballot(fl);
        int lane = t & 63;
        if (lane == 0)  bA[p >> 5] = (unsigned int)m;
        if (lane == 32) bA[p >> 5] = (unsigned int)(m >> 32);
    }
    __syncthreads();

    // horizontal 5-tap erosion, OOB = 1 (minpool pads with +inf)
    for (int q = t; q < 600; q += 256) {
        int w = q % 5;
        unsigned int cur = bA[q];
        unsigned int left  = (w > 0) ? bA[q - 1] : 0xFFFFFFFFu;
        unsigned int right = (w < 4) ? bA[q + 1] : 0xFFFFFFFFu;
        unsigned int sL1 = (cur >> 1) | (right << 31);
        unsigned int sL2 = (cur >> 2) | (right << 30);
        unsigned int sR1 = (cur << 1) | (left >> 31);
        unsigned int sR2 = (cur << 2) | (left >> 30);
        bB[q] = cur & sL1 & sL2 & sR1 & sR2;
    }
    __syncthreads();

    // vertical 5-tap erosion (OOB rows = 1)
    for (int q = t; q < 600; q += 256) {
        int h = q / 5, w = q - h * 5;
        unsigned int v = 0xFFFFFFFFu;
#pragma unroll
        for (int dh = -2; dh <= 2; ++dh) {
            int hh = h + dh;
            if (hh >= 0 && hh < HH) v &= bB[hh * 5 + w];
        }
        bA[q] = v;
    }
    __syncthreads();

    // stuff_depth into padded LDS
    for (int it = 0; it < HW / 256; ++it) {
        int p = it * 256 + t;
        int h = p / WW, w = p - h * WW;
        unsigned int bit = (bA[p >> 5] >> (p & 31)) & 1u;
        float d = fminf(dp[p], DMAXF);
        sd[h * SDP + w] = bit ? d : 0.f;
    }
    __syncthreads();

    if (t < HH) { float m = -INFINITY; for (int w = 0; w < WW; w++) m = fmaxf(m, sd[t * SDP + w]); ymax[t] = m; }
    if (t < WW) { float m = -INFINITY; for (int h = 0; h < HH; h++) m = fmaxf(m, sd[h * SDP + t]); xmax[t] = m; }
    __syncthreads();

    if (t == 0) {
        float f = 0.f, l = 0.f;
        for (int h = 0; h < HH; h++) { if (ymax[h] != 0.f) { f = ymax[h]; break; } }
        for (int h = HH - 1; h >= 0; h--) { if (ymax[h] != 0.f) { l = ymax[h]; break; } }
        vv[0] = f; vv[1] = l;
    }
    if (t == 1) {
        float f = 0.f, l = 0.f;
        for (int w = 0; w < WW; w++) { if (xmax[w] != 0.f) { f = xmax[w]; break; } }
        for (int w = WW - 1; w >= 0; w--) { if (xmax[w] != 0.f) { l = xmax[w]; break; } }
        vv[2] = f; vv[3] = l;
    }
    __syncthreads();
    float v1 = vv[0], v2 = vv[1], v3 = vv[2], v4 = vv[3];

    // fill order matches reference: col updates (last) override row updates at corners
    auto sdval = [&](int h, int w) -> float {
        float x = sd[h * SDP + w];
        if (w == 0)      return (x == 0.f) ? v3 : x;
        if (w == WW - 1) return (x == 0.f) ? v4 : x;
        if (h == 0)      return (x == 0.f) ? v1 : x;
        if (h == HH - 1) return (x == 0.f) ? v2 : x;
        return x;
    };
    if (t < WW) { float m = -INFINITY; for (int h = 0; h < HH; h++) m = fmaxf(m, sdval(h, t)); colmax[t] = m; }
    if (t < HH) { float m = -INFINITY; for (int w = 0; w < WW; w++) m = fmaxf(m, sdval(t, w)); rowmax[t] = m; }
    __syncthreads();

    if (t == 0) {  // find_none on colmax (len W) -> sxv
        float m = INFINITY;
        for (int i = WW - 1; i >= 0; i--) { sufc[i] = m; float a = colmax[i]; if (a != 0.f) m = fminf(m, a); }
        m = INFINITY;
        for (int i = 0; i < WW; i++) {
            float a = colmax[i];
            float l = (m == INFINITY) ? 0.f : m;
            float r = (sufc[i] == INFINITY) ? 0.f : sufc[i];
            float val = (a == 0.f) ? fmaxf(l, r) : a;
            if (val != 0.f) m = fminf(m, val);
            sxv[i] = val;
        }
    }
    if (t == 1) {  // find_none on rowmax (len H) -> syv
        float m = INFINITY;
        for (int i = HH - 1; i >= 0; i--) { sufr[i] = m; float a = rowmax[i]; if (a != 0.f) m = fminf(m, a); }
        m = INFINITY;
        for (int i = 0; i < HH; i++) {
            float a = rowmax[i];
            float l = (m == INFINITY) ? 0.f : m;
            float r = (sufr[i] == INFINITY) ? 0.f : sufr[i];
            float val = (a == 0.f) ? fmaxf(l, r) : a;
            if (val != 0.f) m = fminf(m, val);
            syv[i] = val;
        }
    }
    __syncthreads();

    // depth_max_bins for every pixel of this batch
    for (int it = 0; it < HW / 256; ++it) {
        int p = it * 256 + t;
        int h = p / WW, w = p - h * WW;
        float dm = fminf(sxv[w], syv[h]);
        dmb_arr[b * HW + p] = (int)((dm / DMAXF) * 100.0f);
    }
}

// ---------------- K4: features writer, 4 pixels/thread ----------------
__device__ inline void comp1(float o, int di, int db, int bin, float& dw, float& sg, float& ad) {
    bool dwk = (bin > di - 3) && (bin < db + 5);
    float s = 1.f / (1.f + __expf(-o));
    dw = dwk ? s : 0.f;
    float df = ((float)(bin - di)) / 100.0f * DMAXF;
    sg = (float)((bin > di) - (bin < di));
    ad = fabsf(df);
}

__global__ void k4_features(const float4* __restrict__ occ4, const float4* __restrict__ fs4,
                            const int4* __restrict__ di4, const int4* __restrict__ dmb4,
                            float4* __restrict__ out4) {
    const int HW4 = HW / 4;
    int t = blockIdx.x * blockDim.x + threadIdx.x;
    if (t >= BB * NB * HW4) return;
    int b = t / (NB * HW4);
    int r = t - b * (NB * HW4);
    int bin = r / HW4;
    int p4 = r - bin * HW4;
    int4 di = di4[b * HW4 + p4];
    int4 db = dmb4[b * HW4 + p4];
    float4 o = occ4[t];
    float4 dw, sgn, adf;
    comp1(o.x, di.x, db.x, bin, dw.x, sgn.x, adf.x);
    comp1(o.y, di.y, db.y, bin, dw.y, sgn.y, adf.y);
    comp1(o.z, di.z, db.z, bin, dw.z, sgn.z, adf.z);
    comp1(o.w, di.w, db.w, bin, dw.w, sgn.w, adf.w);
    size_t base = (size_t)(b * 15 * NB + bin) * HW4 + p4;
    const float4* fp = fs4 + (size_t)b * KK * HW4 + p4;
#pragma unroll
    for (int c = 0; c < KK; c++) out4[base + (size_t)c * NB * HW4] = fp[(size_t)c * HW4];
    out4[base + (size_t)12 * NB * HW4] = dw;
    out4[base + (size_t)13 * NB * HW4] = sgn;
    out4[base + (size_t)14 * NB * HW4] = adf;
}

// ---------------- K5: voxel gather + bit-pack ----------------
__global__ void k5_gather(const int* __restrict__ kept, const float4* __restrict__ mapping,
                          const int* __restrict__ di_arr, const int* __restrict__ dmb_arr,
                          float* __restrict__ out_fk, unsigned int* __restrict__ fk_pk,
                          unsigned int* __restrict__ kept_pk) {
    int v = blockIdx.x * blockDim.x + threadIdx.x;
    float4 m = mapping[v];
    int bi = (int)m.x, xi = (int)m.y, yi = (int)m.z;
    int dIdx = (int)((m.w * 100.0f) / DMAXF);   // exact op order: mul then div
    int kp = kept[v];
    int pp = bi * HW + yi * WW + xi;
    int di = di_arr[pp], db = dmb_arr[pp];
    bool dwk = (dIdx > di - 3) && (dIdx < db + 5);
    bool fk = (kp != 0) && dwk;
    out_fk[v] = fk ? 1.f : 0.f;
    unsigned long long mb = __ballot(fk);
    unsigned long long mk = __ballot(kp != 0);
    int lane = threadIdx.x & 63;
    if (lane == 0)  { fk_pk[v >> 5] = (unsigned int)mb;         kept_pk[v >> 5] = (unsigned int)mk; }
    if (lane == 32) { fk_pk[v >> 5] = (unsigned int)(mb >> 32); kept_pk[v >> 5] = (unsigned int)(mk >> 32); }
}

// ---------------- bitwise 128-bit k-dilation ----------------
__device__ inline void kdil128(unsigned int w0, unsigned int w1, unsigned int w2, unsigned int w3,
                               unsigned int* r) {
    unsigned int a0 = w0, a1 = w1, a2 = w2, a3 = w3;
    a0 |= w0 << 1; a1 |= (w1 << 1) | (w0 >> 31); a2 |= (w2 << 1) | (w1 >> 31); a3 |= (w3 << 1) | (w2 >> 31);
    a0 |= w0 << 2; a1 |= (w1 << 2) | (w0 >> 30); a2 |= (w2 << 2) | (w1 >> 30); a3 |= (w3 << 2) | (w2 >> 30);
    a0 |= (w0 >> 1) | (w1 << 31); a1 |= (w1 >> 1) | (w2 << 31); a2 |= (w2 >> 1) | (w3 << 31); a3 |= w3 >> 1;
    a0 |= (w0 >> 2) | (w1 << 30); a1 |= (w1 >> 2) | (w2 << 30); a2 |= (w2 >> 2) | (w3 << 30); a3 |= w3 >> 2;
    r[0] = a0; r[1] = a1; r[2] = a2; r[3] = a3;
}

// ---------------- K6: dilate along j, then k (per line); also zero-init counters ----------------
__global__ void k6_dil_jk(const uint4* __restrict__ in, uint4* __restrict__ outb,
                          int* __restrict__ counters) {
    int l = blockIdx.x * blockDim.x + threadIdx.x;
    if (l == 0) { counters[0] = 0; counters[1] = 0; }
    int b = l / (DD * DD); int rem = l - b * DD * DD; int i = rem / DD; int j = rem - i * DD;
    unsigned int a0 = 0, a1 = 0, a2 = 0, a3 = 0;
#pragma unroll
    for (int dj = -2; dj <= 2; dj++) {
        int jj = j + dj; if (jj < 0 || jj >= DD) continue;
        uint4 x = in[(b * DD + i) * DD + jj];
        a0 |= x.x; a1 |= x.y; a2 |= x.z; a3 |= x.w;
    }
    unsigned int r[4];
    kdil128(a0, a1, a2, a3, r);
    outb[l] = make_uint4(r[0], r[1], r[2], r[3]);
}

// ---------------- K7: dilate along i, AND kept, any-flag -> counters ----------------
__global__ void k7_dil_i_count(const uint4* __restrict__ tmp1, const uint4* __restrict__ kept_pk,
                               uint4* __restrict__ pad0, int* __restrict__ counters) {
    int l = blockIdx.x * blockDim.x + threadIdx.x;
    int b = l / (DD * DD); int rem = l - b * DD * DD; int i = rem / DD; int j = rem - i * DD;
    unsigned int a0 = 0, a1 = 0, a2 = 0, a3 = 0;
#pragma unroll
    for (int di = -2; di <= 2; di++) {
        int ii = i + di; if (ii < 0 || ii >= DD) continue;
        uint4 x = tmp1[(b * DD + ii) * DD + j];
        a0 |= x.x; a1 |= x.y; a2 |= x.z; a3 |= x.w;
    }
    uint4 kk = kept_pk[l];
    a0 &= kk.x; a1 &= kk.y; a2 &= kk.z; a3 &= kk.w;
    pad0[l] = make_uint4(a0, a1, a2, a3);
    // only ==0 is ever tested downstream -> an any-flag suffices (wave b is uniform)
    unsigned long long bal = __ballot((a0 | a1 | a2 | a3) != 0u);
    if ((threadIdx.x & 63) == 0 && bal) atomicOr(&counters[b], 1);
}

// ---------------- K8: fused finalize (special-set, &~fk) + 2x2x2 block-any + union ----------------
__global__ void k8ab_union(const uint4* __restrict__ pad0, const uint4* __restrict__ fk_pk,
                           const int* __restrict__ counters, uint4* __restrict__ uni) {
    int l = blockIdx.x * blockDim.x + threadIdx.x;
    int b = l >> 14; int rem = l & 16383; int i = rem >> 7; int j = rem & 127;
    uint4 u = fk_pk[l];
    if (((i | j) & 1) == 0) {
        bool c0 = (counters[b] == 0);
        unsigned int q0 = 0, q1 = 0, q2 = 0, q3 = 0;
#pragma unroll
        for (int di2 = 0; di2 < 2; di2++)
#pragma unroll
            for (int dj2 = 0; dj2 < 2; dj2++) {
                int ii = i + di2, jj = j + dj2;
                int ll = (b * DD + ii) * DD + jj;
                uint4 p = pad0[ll]; uint4 f = fk_pk[ll];
                unsigned int pw = p.w;
                if (c0 && ii == 127 && jj == 127) pw |= 0x80000000u;  // bit 127 special
                q0 |= p.x & ~f.x; q1 |= p.y & ~f.y; q2 |= p.z & ~f.z; q3 |= pw & ~f.w;
            }
        q0 = (q0 | (q0 >> 1)) & 0x55555555u;
        q1 = (q1 | (q1 >> 1)) & 0x55555555u;
        q2 = (q2 | (q2 >> 1)) & 0x55555555u;
        q3 = (q3 | (q3 >> 1)) & 0x55555555u;
        u.x |= q0; u.y |= q1; u.z |= q2; u.w |= q3;
    }
    uni[l] = u;
}

// ---------------- K11f: fused i-dilation + unpack to floats (4 voxels/thread) ----------------
__global__ void k11f_dil_unpack(const unsigned int* __restrict__ tmp1w, float4* __restrict__ outm) {
    int t = blockIdx.x * blockDim.x + threadIdx.x;   // NVOX/4 threads
    int vb = t << 2;
    int line = vb >> 7;
    int wi = (vb >> 5) & 3;
    int bo = vb & 31;
    int b = line >> 14; int rem = line & 16383; int i = rem >> 7; int j = rem & 127;
    unsigned int w = 0;
#pragma unroll
    for (int di = -2; di <= 2; di++) {
        int ii = i + di;
        if (ii >= 0 && ii < DD) w |= tmp1w[((b * DD + ii) * DD + j) * 4 + wi];
    }
    float4 r;
    r.x = (float)((w >> bo) & 1u);
    r.y = (float)((w >> (bo + 1)) & 1u);
    r.z = (float)((w >> (bo + 2)) & 1u);
    r.w = (float)((w >> (bo + 3)) & 1u);
    outm[t] = r;
}

extern "C" void kernel_launch(void* const* d_in, const int* in_sizes, int n_in,
                              void* d_out, int out_size, void* d_ws, size_t ws_size,
                              hipStream_t stream) {
    (void)in_sizes; (void)n_in; (void)out_size; (void)ws_size;
    const float* sem2d   = (const float*)d_in[0];
    const float* depth   = (const float*)d_in[1];
    const float* occ     = (const float*)d_in[2];
    const int*   kept    = (const int*)d_in[3];
    const float* mapping = (const float*)d_in[4];
    float* out = (float*)d_out;

    // workspace carve-up (all segment offsets multiple of 16 B)
    float* feats_sm    = (float*)d_ws;                 // B*K*HW
    float* stuffflag   = feats_sm + BB * KK * HW;      // B*HW
    int*   di_arr      = (int*)(stuffflag + BB * HW);  // B*HW
    int*   dmb_arr     = di_arr + BB * HW;             // B*HW
    unsigned int* fk_pk   = (unsigned int*)(dmb_arr + BB * HW); // NVOX/32 each
    unsigned int* kept_pk = fk_pk + NVOX / 32;
    unsigned int* tmp1    = kept_pk + NVOX / 32;
    unsigned int* pad0    = tmp1 + NVOX / 32;
    unsigned int* uni     = pad0 + NVOX / 32;
    int* counters = (int*)(uni + NVOX / 32);

    k1_pixel<<<BB * HW / 256, 256, 0, stream>>>(sem2d, depth, feats_sm, stuffflag, di_arr);
    k23_stuff<<<BB, 256, 0, stream>>>(stuffflag, depth, dmb_arr);

    k4_features<<<BB * NB * (HW / 4) / 256, 256, 0, stream>>>(
        (const float4*)occ, (const float4*)feats_sm, (const int4*)di_arr, (const int4*)dmb_arr,
        (float4*)out);

    k5_gather<<<NVOX / 256, 256, 0, stream>>>(kept, (const float4*)mapping, di_arr, dmb_arr,
                                              out + (size_t)57600000, fk_pk, kept_pk);

    int lineBlocks = NLINES / 256;
    k6_dil_jk<<<lineBlocks, 256, 0, stream>>>((const uint4*)fk_pk, (uint4*)tmp1, counters);
    k7_dil_i_count<<<lineBlocks, 256, 0, stream>>>((const uint4*)tmp1, (const uint4*)kept_pk,
                                                   (uint4*)pad0, counters);
    k8ab_union<<<lineBlocks, 256, 0, stream>>>((const uint4*)pad0, (const uint4*)fk_pk, counters,
                                               (uint4*)uni);
    k6_dil_jk<<<lineBlocks, 256, 0, stream>>>((const uint4*)uni, (uint4*)tmp1, counters);
    k11f_dil_unpack<<<NVOX / 4 / 256, 256, 0, stream>>>(tmp1, (float4*)(out + (size_t)61794304));
}